// Round 8
// baseline (239.244 us; speedup 1.0000x reference)
//
#include <hip/hip_runtime.h>
#include <hip/hip_bf16.h>
#include <math.h>

// Problem constants
#define BATCH 8
#define SEQ   2048
#define CH    512
#define ROWS  (BATCH * SEQ)   // 16384
#define INVSQ 0.044194173824159216f  // 1/sqrt(512)

#define TP 68                  // transpose-tile pitch (2-way conflict = free)

typedef __attribute__((ext_vector_type(8))) __bf16 bf16x8;
typedef __attribute__((ext_vector_type(4))) float f32x4;

__device__ inline unsigned short f2bf(float f) {
    unsigned u = __builtin_bit_cast(unsigned, f);
    u += 0x7fffu + ((u >> 16) & 1u);   // round-to-nearest-even
    return (unsigned short)(u >> 16);
}
__device__ inline float bf2f(unsigned short s) {
    unsigned u = ((unsigned)s) << 16;
    return __builtin_bit_cast(float, u);
}

// ---------------------------------------------------------------------------
// fuse_x: x fp32 [16384,512] -> out[:, :, 0:512] (fp32) AND xb (bf16).
// Also zeroes Z (blocks 0..63).
// ---------------------------------------------------------------------------
__global__ __launch_bounds__(256) void fuse_x_kernel(
    const float* __restrict__ x, unsigned short* __restrict__ xb,
    float* __restrict__ out, float* __restrict__ Z)
{
    if (blockIdx.x < 64) Z[blockIdx.x * 256 + threadIdx.x] = 0.f;
    size_t base = ((size_t)blockIdx.x * 256 + threadIdx.x) * 8;
    size_t row = base >> 9, c = base & 511;
    float4 v0 = *(const float4*)(x + base);
    float4 v1 = *(const float4*)(x + base + 4);
    float* o = out + row * 1024 + c;
    *(float4*)o = v0;
    *(float4*)(o + 4) = v1;
    alignas(16) unsigned short t[8];
    t[0] = f2bf(v0.x); t[1] = f2bf(v0.y); t[2] = f2bf(v0.z); t[3] = f2bf(v0.w);
    t[4] = f2bf(v1.x); t[5] = f2bf(v1.y); t[6] = f2bf(v1.z); t[7] = f2bf(v1.w);
    *(uint4*)(xb + base) = *(const uint4*)t;
}

// ---------------------------------------------------------------------------
// transpose_w: W fp32 [512 k][512 n] -> Wt bf16 [3][512 n][512 k]
// ---------------------------------------------------------------------------
__global__ __launch_bounds__(256) void transpose_w_kernel(
    const float* __restrict__ Wq, const float* __restrict__ Wk,
    const float* __restrict__ Wv, unsigned short* __restrict__ Wt)
{
    __shared__ unsigned short T[64 * TP];
    const int k0 = blockIdx.x * 64, n0 = blockIdx.y * 64, w = blockIdx.z;
    const float* W = (w == 0) ? Wq : (w == 1) ? Wk : Wv;
    const int tid = threadIdx.x;
#pragma unroll
    for (int i = 0; i < 2; ++i) {
        int slot = tid + i * 256;
        int kr = slot >> 3, c8 = (slot & 7) << 3;
        float4 a = *(const float4*)(W + (size_t)(k0 + kr) * CH + n0 + c8);
        float4 b = *(const float4*)(W + (size_t)(k0 + kr) * CH + n0 + c8 + 4);
        T[(c8 + 0) * TP + kr] = f2bf(a.x); T[(c8 + 1) * TP + kr] = f2bf(a.y);
        T[(c8 + 2) * TP + kr] = f2bf(a.z); T[(c8 + 3) * TP + kr] = f2bf(a.w);
        T[(c8 + 4) * TP + kr] = f2bf(b.x); T[(c8 + 5) * TP + kr] = f2bf(b.y);
        T[(c8 + 6) * TP + kr] = f2bf(b.z); T[(c8 + 7) * TP + kr] = f2bf(b.w);
    }
    __syncthreads();
#pragma unroll
    for (int i = 0; i < 2; ++i) {
        int slot = tid + i * 256;
        int nr = slot >> 3, k8 = (slot & 7) << 3;
        uint2 lo = *(const uint2*)(T + nr * TP + k8);
        uint2 hi = *(const uint2*)(T + nr * TP + k8 + 4);
        uint4 u; u.x = lo.x; u.y = lo.y; u.z = hi.x; u.w = hi.y;
        *(uint4*)(Wt + ((size_t)w * CH + n0 + nr) * CH + k0 + k8) = u;
    }
}

// ---------------------------------------------------------------------------
// transpose_v: vb bf16 [b][s][v] -> Vt bf16 [b][v][s], scaled by 1/Z[b][s].
// ---------------------------------------------------------------------------
__global__ __launch_bounds__(256) void transpose_v_kernel(
    const unsigned short* __restrict__ vb, const float* __restrict__ Z,
    unsigned short* __restrict__ Vt)
{
    __shared__ unsigned short T[64 * TP];
    const int s0 = blockIdx.x * 64, v0 = blockIdx.y * 64, b = blockIdx.z;
    const int tid = threadIdx.x;
#pragma unroll
    for (int i = 0; i < 2; ++i) {
        int slot = tid + i * 256;
        int sr = slot >> 3, c8 = (slot & 7) << 3;
        float inv = 1.0f / Z[b * SEQ + s0 + sr];
        uint4 raw = *(const uint4*)(vb + ((size_t)b * SEQ + s0 + sr) * CH + v0 + c8);
        const unsigned short* p = (const unsigned short*)&raw;
#pragma unroll
        for (int j = 0; j < 8; ++j)
            T[(c8 + j) * TP + sr] = f2bf(bf2f(p[j]) * inv);
    }
    __syncthreads();
#pragma unroll
    for (int i = 0; i < 2; ++i) {
        int slot = tid + i * 256;
        int vr = slot >> 3, s8 = (slot & 7) << 3;
        uint2 lo = *(const uint2*)(T + vr * TP + s8);
        uint2 hi = *(const uint2*)(T + vr * TP + s8 + 4);
        uint4 u; u.x = lo.x; u.y = lo.y; u.z = hi.x; u.w = hi.y;
        *(uint4*)(Vt + ((size_t)b * CH + v0 + vr) * SEQ + s0 + s8) = u;
    }
}

// ===========================================================================
// 256x256-tile BK=32 TRIPLE-BUFFERED counted-vmcnt pipeline, 512 thr/8 waves.
// LDS 96 KB: A[3][256][32] | B[3][256][32] bf16 (64-B rows, 16 KB slabs).
// Wave-tile 128(A-rows, waveA=wave>>2) x 64(B-rows, waveB=wave&3), acc[8][4].
// Swizzle: involution slot ^= (row>>2)&3 on 16-B slots within each 64-B row
// (both sides: pre-swizzled global source col, matching read slot) ->
// 16 lanes spread 2-way per bank group = free.
// Per K-tile U (NT=16), 2 phases of 16 MFMA:
//  P1: stageA(U+2) | read b[0-3],a[0-3] | bar | lgkm(0) | MFMA rows0-3 | bar
//  P2: stageB(U+2) | read a[4-7] | bar | lgkm(0) | MFMA rows4-7 |
//      vmcnt(4) [U<=NT-3] / vmcnt(0) [U==NT-2] | bar
// Counted-vmcnt invariants (per-wave, 2 DMA instrs per stage-event):
//  at tile-U end outstanding = {U+1:4, U+2:4}; vmcnt(4) drains U+1's ->
//  tile U+1's slabs landed, U+2's stay in flight (2-tile prefetch distance
//  ~1000cyc > HBM 900cyc). WAR: stage(U+2) targets buf[(U+2)%3]=buf[(U-1)%3],
//  whose ds_reads all retired (lgkm(0)) before tile U-1's closing barrier.
//  RAW: tile U's slabs drained by tile U-1's vmcnt+barrier (cross-wave pub).
// ===========================================================================
#define STAGE2x(gsrc, dslab)                                                  \
    _Pragma("unroll")                                                         \
    for (int j = 0; j < 2; ++j)                                               \
        __builtin_amdgcn_global_load_lds(                                     \
            (const __attribute__((address_space(1))) unsigned int*)((gsrc) + (size_t)j * 128 * gstride), \
            (__attribute__((address_space(3))) unsigned int*)((dslab) + j * 4096 + (tid << 3)), \
            16, 0, 0);

#define PIPE256_T3(NT)                                                        \
    stageA(0); stageB(0); stageA(1); stageB(1);                               \
    asm volatile("s_waitcnt vmcnt(4)" ::: "memory");                          \
    __builtin_amdgcn_s_barrier();                                             \
    __builtin_amdgcn_sched_barrier(0);                                        \
    _Pragma("unroll")                                                         \
    for (int U = 0; U < (NT); ++U) {                                          \
        const unsigned short* Ab = lds + (U % 3) * 8192;                      \
        const unsigned short* Bb = lds + 24576 + (U % 3) * 8192;              \
        bf16x8 a[4], b[4];                                                    \
        /* ---- P1 ---- */                                                    \
        stageA(U + 2);                                                        \
        _Pragma("unroll")                                                     \
        for (int n = 0; n < 4; ++n)                                           \
            b[n] = *(const bf16x8*)(Bb + (brow + n * 16) * 32 + s8w);         \
        _Pragma("unroll")                                                     \
        for (int r = 0; r < 4; ++r)                                           \
            a[r] = *(const bf16x8*)(Ab + (arow + r * 16) * 32 + s8w);         \
        __builtin_amdgcn_s_barrier();                                         \
        asm volatile("s_waitcnt lgkmcnt(0)" ::: "memory");                    \
        __builtin_amdgcn_sched_barrier(0);                                    \
        __builtin_amdgcn_s_setprio(1);                                        \
        _Pragma("unroll")                                                     \
        for (int r = 0; r < 4; ++r)                                           \
            _Pragma("unroll")                                                 \
            for (int c = 0; c < 4; ++c)                                       \
                acc[r][c] = __builtin_amdgcn_mfma_f32_16x16x32_bf16(          \
                    a[r], b[c], acc[r][c], 0, 0, 0);                          \
        __builtin_amdgcn_s_setprio(0);                                        \
        __builtin_amdgcn_s_barrier();                                         \
        __builtin_amdgcn_sched_barrier(0);                                    \
        /* ---- P2 ---- */                                                    \
        stageB(U + 2);                                                        \
        _Pragma("unroll")                                                     \
        for (int r = 0; r < 4; ++r)                                           \
            a[r] = *(const bf16x8*)(Ab + (arow + 64 + r * 16) * 32 + s8w);    \
        __builtin_amdgcn_s_barrier();                                         \
        asm volatile("s_waitcnt lgkmcnt(0)" ::: "memory");                    \
        __builtin_amdgcn_sched_barrier(0);                                    \
        __builtin_amdgcn_s_setprio(1);                                        \
        _Pragma("unroll")                                                     \
        for (int r = 0; r < 4; ++r)                                           \
            _Pragma("unroll")                                                 \
            for (int c = 0; c < 4; ++c)                                       \
                acc[r + 4][c] = __builtin_amdgcn_mfma_f32_16x16x32_bf16(      \
                    a[r], b[c], acc[r + 4][c], 0, 0, 0);                      \
        __builtin_amdgcn_s_setprio(0);                                        \
        if (U <= (NT) - 3)      asm volatile("s_waitcnt vmcnt(4)" ::: "memory"); \
        else if (U == (NT) - 2) asm volatile("s_waitcnt vmcnt(0)" ::: "memory"); \
        __builtin_amdgcn_s_barrier();                                         \
        __builtin_amdgcn_sched_barrier(0);                                    \
    }

// ---------------------------------------------------------------------------
// qkv fused GEMM, 256x256: A = Wt (256 weight rows), B = xb (256 x rows),
// K=512 -> NT=16. Grid 384 = 64 xt x 6 wt, bijective XCD swizzle (8x48).
// ---------------------------------------------------------------------------
__global__ __launch_bounds__(512) void qkv8_kernel(
    const unsigned short* __restrict__ xb, const unsigned short* __restrict__ Wt,
    const float* __restrict__ bq, const float* __restrict__ bk,
    const float* __restrict__ bv, unsigned short* __restrict__ qkv)
{
    __shared__ unsigned short lds[49152];   // 96 KB
    const int tid = threadIdx.x;
    const int lane = tid & 63, wave = tid >> 6;
    const int waveA = wave >> 2;            // 0..1: weight strip (128 rows)
    const int waveB = wave & 3;             // 0..3: x strip (64 rows)
    const int quad = lane >> 4, l16 = lane & 15;

    int id = (int)blockIdx.x;
    id = (id & 7) * 48 + (id >> 3);         // bijective XCD swizzle
    const int xt = id / 6, wt = id - xt * 6;
    const int xrow0 = xt << 8, wrow0 = wt << 8;

    const size_t gstride = CH;
    const unsigned short* __restrict__ Ag = Wt + (size_t)wrow0 * CH;
    const unsigned short* __restrict__ Bg = xb + (size_t)xrow0 * CH;

    // Stage source: row = j*128 + (tid>>2), slot = (tid&3)^((row>>2)&3);
    // (row>>2)&3 == (tid>>4)&3 since j*128>>2 == 0 mod 4.
    const int scol = (((tid & 3) ^ ((tid >> 4) & 3)) << 3);
    const size_t ga = (size_t)(tid >> 2) * gstride + scol;
    // Read slot: (quad)^((row>>2)&3); row = strip + l16 -> (row>>2)&3 ==
    // (l16>>2)&3 (strips are multiples of 64).
    const int s8w = ((quad ^ ((l16 >> 2) & 3)) << 3);
    const int arow = waveA * 128 + l16;
    const int brow = waveB * 64 + l16;

    f32x4 acc[8][4] = {};

    auto stageA = [&](int V) {
        if (V >= 16) return;
        const unsigned short* g = Ag + ga + V * 32;
        unsigned short* d = lds + (V % 3) * 8192;
        STAGE2x(g, d)
    };
    auto stageB = [&](int V) {
        if (V >= 16) return;
        const unsigned short* g = Bg + ga + V * 32;
        unsigned short* d = lds + 24576 + (V % 3) * 8192;
        STAGE2x(g, d)
    };

    PIPE256_T3(16)

    const int which = wrow0 >> 9;   // uniform per block
    const float* bias = (which == 0) ? bq : (which == 1) ? bk : bv;
    const float scale = (which == 0) ? INVSQ : 1.0f;
    unsigned short* outw = qkv + (size_t)which * ROWS * CH;
    const int colblk = wrow0 & 511;
#pragma unroll
    for (int r = 0; r < 8; ++r) {
        int colb = colblk + waveA * 128 + r * 16 + quad * 4;
        float4 b4 = *(const float4*)(bias + colb);
#pragma unroll
        for (int c = 0; c < 4; ++c) {
            int m = xrow0 + waveB * 64 + c * 16 + l16;
            alignas(8) unsigned short pk[4];
            pk[0] = f2bf((acc[r][c][0] + b4.x) * scale);
            pk[1] = f2bf((acc[r][c][1] + b4.y) * scale);
            pk[2] = f2bf((acc[r][c][2] + b4.z) * scale);
            pk[3] = f2bf((acc[r][c][3] + b4.w) * scale);
            *(uint2*)(outw + (size_t)m * CH + colb) = *(const uint2*)pk;
        }
    }
}

// ---------------------------------------------------------------------------
// logits, 256x256: C[s][t] = k_s . q_t (q pre-scaled). Triangle st<=tt over
// 8x8 256-tiles: 36 pairs x 8 batches = 288 blocks, b = blockIdx&7 pins XCD.
// E[t][s] = exp(C) if s<=t else 0; Z[s] via shuffle+atomic. (Epilogue and
// mapping verified in round 7.)
// ---------------------------------------------------------------------------
__global__ __launch_bounds__(512) void logits8_kernel(
    const unsigned short* __restrict__ qb, const unsigned short* __restrict__ kb,
    unsigned short* __restrict__ E, float* __restrict__ Z)
{
    __shared__ unsigned short lds[49152];   // 96 KB
    const int tid = threadIdx.x;
    const int lane = tid & 63, wave = tid >> 6;
    const int waveA = wave >> 2;            // 0..1: s strip (128 rows)
    const int waveB = wave & 3;             // 0..3: t strip (64 rows)
    const int quad = lane >> 4, l16 = lane & 15;

    const int b = (int)blockIdx.x & 7;
    const int i = (int)blockIdx.x >> 3;     // 0..35 triangle index
    int tt = (int)((sqrtf(8.f * (float)i + 1.f) - 1.f) * 0.5f);
    int st = i - ((tt * (tt + 1)) >> 1);
    while (st < 0)  { --tt; st = i - ((tt * (tt + 1)) >> 1); }
    while (st > tt) { ++tt; st = i - ((tt * (tt + 1)) >> 1); }
    const int m0s = st << 8;    // s rows (A, from k), 256-wide
    const int n0t = tt << 8;    // t rows (B, from q), 256-wide

    const size_t gstride = CH;
    const unsigned short* __restrict__ Ag = kb + ((size_t)b * SEQ + m0s) * CH;
    const unsigned short* __restrict__ Bg = qb + ((size_t)b * SEQ + n0t) * CH;

    const int scol = (((tid & 3) ^ ((tid >> 4) & 3)) << 3);
    const size_t ga = (size_t)(tid >> 2) * gstride + scol;
    const int s8w = ((quad ^ ((l16 >> 2) & 3)) << 3);
    const int arow = waveA * 128 + l16;
    const int brow = waveB * 64 + l16;

    f32x4 acc[8][4] = {};

    auto stageA = [&](int V) {
        if (V >= 16) return;
        const unsigned short* g = Ag + ga + V * 32;
        unsigned short* d = lds + (V % 3) * 8192;
        STAGE2x(g, d)
    };
    auto stageB = [&](int V) {
        if (V >= 16) return;
        const unsigned short* g = Bg + ga + V * 32;
        unsigned short* d = lds + 24576 + (V % 3) * 8192;
        STAGE2x(g, d)
    };

    PIPE256_T3(16)

    // Epilogue: causal mask, exp, Z partial sums, bf16 E write.
#pragma unroll
    for (int r = 0; r < 8; ++r) {
        int sb = m0s + waveA * 128 + r * 16 + quad * 4;
        float ev[4][4];
#pragma unroll
        for (int c = 0; c < 4; ++c) {
            int t = n0t + waveB * 64 + c * 16 + l16;
#pragma unroll
            for (int reg = 0; reg < 4; ++reg)
                ev[c][reg] = (sb + reg <= t) ? __expf(acc[r][c][reg]) : 0.f;
        }
#pragma unroll
        for (int reg = 0; reg < 4; ++reg) {
            float z = ev[0][reg] + ev[1][reg] + ev[2][reg] + ev[3][reg];
            z += __shfl_xor(z, 1);
            z += __shfl_xor(z, 2);
            z += __shfl_xor(z, 4);
            z += __shfl_xor(z, 8);
            if (l16 == 0) atomicAdd(&Z[b * SEQ + sb + reg], z);
        }
#pragma unroll
        for (int c = 0; c < 4; ++c) {
            int t = n0t + waveB * 64 + c * 16 + l16;
            alignas(8) unsigned short pk[4];
            pk[0] = f2bf(ev[c][0]); pk[1] = f2bf(ev[c][1]);
            pk[2] = f2bf(ev[c][2]); pk[3] = f2bf(ev[c][3]);
            *(uint2*)(E + ((size_t)b * SEQ + t) * SEQ + sb) = *(const uint2*)pk;
        }
    }
}

// ---------------------------------------------------------------------------
// read (round-6 version, verified): C[v][t] = sum_s Vt[v][s] * E[t][s].
// 128x128, BK=64, A 2-buf + B 3-buf (80 KB), single-barrier deep pipeline.
// ---------------------------------------------------------------------------
#define R_STAGE4(gsrc, dslab)                                                 \
    _Pragma("unroll")                                                         \
    for (int p = 0; p < 4; ++p)                                               \
        __builtin_amdgcn_global_load_lds(                                     \
            (const __attribute__((address_space(1))) unsigned int*)((gsrc) + (size_t)p * 32 * gstride), \
            (__attribute__((address_space(3))) unsigned int*)((dslab) + p * 2048 + (tid << 3)), \
            16, 0, 0);

__global__ __launch_bounds__(256, 2) void read8_kernel(
    const unsigned short* __restrict__ E, const unsigned short* __restrict__ Vt,
    float* __restrict__ out)
{
    __shared__ unsigned short lds[40960];   // 80 KB
    const int tid = threadIdx.x;
    const int lane = tid & 63, wave = tid >> 6;
    const int waveA = wave >> 1;            // 0..1: v strip
    const int waveB = wave & 1;             // 0..1: t strip
    const int quad = lane >> 4, l16 = lane & 15;

    const int id = blockIdx.x;
    const int b = id & 7;
    const int rem = id >> 3;
    const int mv = rem & 3;                  // v tile (4)
    const int r0 = rem >> 2;                 // 0..15
    const int tt = (r0 < 8) ? r0 : 23 - r0;  // paired so per-CU work balances
    const int m0v = mv << 7;
    const int n0t = tt << 7;
    const int NT = (tt + 1) * 2;             // K-tiles of 64 (causal extent)

    const size_t gstride = SEQ;
    const unsigned short* __restrict__ Ag = Vt + ((size_t)b * CH + m0v) * SEQ;
    const unsigned short* __restrict__ Bg = E + ((size_t)b * SEQ + n0t) * SEQ;

    const int scol = (((tid & 7) ^ ((tid >> 3) & 7)) << 3);
    const size_t ga = (size_t)(tid >> 3) * gstride + scol;
    const int s80 = ((quad ^ (l16 & 7)) << 3);
    const int s81 = s80 ^ 32;
    const int arow = waveA * 64 + l16;
    const int brow = waveB * 64 + l16;

    f32x4 acc[4][4] = {};

    auto stageA = [&](int V) {
        if (V >= NT) return;
        const unsigned short* g = Ag + ga + V * 64;
        unsigned short* d = lds + (V & 1) * 8192;
        R_STAGE4(g, d)
    };
    auto stageB = [&](int V) {
        if (V >= NT) return;
        const unsigned short* g = Bg + ga + V * 64;
        unsigned short* d = lds + 16384 + (V % 3) * 8192;
        R_STAGE4(g, d)
    };

    stageA(0); stageB(0); stageB(1);
    asm volatile("s_waitcnt vmcnt(4)" ::: "memory");
    __builtin_amdgcn_s_barrier();
    __builtin_amdgcn_sched_barrier(0);

#pragma unroll 2
    for (int U = 0; U < NT; ++U) {
        const unsigned short* Ab = lds + (U & 1) * 8192;
        const unsigned short* Bb = lds + 16384 + (U % 3) * 8192;
        stageA(U + 1);
        stageB(U + 2);
        bf16x8 a0[4], a1[4], c0[4], c1[4];
#pragma unroll
        for (int rr = 0; rr < 4; ++rr) {
            a0[rr] = *(const bf16x8*)(Ab + (arow + rr * 16) * 64 + s80);
            c0[rr] = *(const bf16x8*)(Bb + (brow + rr * 16) * 64 + s80);
        }
        __builtin_amdgcn_sched_barrier(0);
#pragma unroll
        for (int rr = 0; rr < 4; ++rr) {
            a1[rr] = *(const bf16x8*)(Ab + (arow + rr * 16) * 64 + s81);
            c1[rr] = *(const bf16x8*)(Bb + (brow + rr * 16) * 64 + s81);
        }
        asm volatile("s_waitcnt lgkmcnt(8)" ::: "memory");
        __builtin_amdgcn_sched_barrier(0);
        __builtin_amdgcn_s_setprio(1);
#pragma unroll
        for (int rr = 0; rr < 4; ++rr)
#pragma unroll
            for (int cc = 0; cc < 4; ++cc)
                acc[rr][cc] = __builtin_amdgcn_mfma_f32_16x16x32_bf16(
                    a0[rr], c0[cc], acc[rr][cc], 0, 0, 0);
        __builtin_amdgcn_s_setprio(0);
        asm volatile("s_waitcnt lgkmcnt(0)" ::: "memory");
        __builtin_amdgcn_sched_barrier(0);
        __builtin_amdgcn_s_setprio(1);
#pragma unroll
        for (int rr = 0; rr < 4; ++rr)
#pragma unroll
            for (int cc = 0; cc < 4; ++cc)
                acc[rr][cc] = __builtin_amdgcn_mfma_f32_16x16x32_bf16(
                    a1[rr], c1[cc], acc[rr][cc], 0, 0, 0);
        __builtin_amdgcn_s_setprio(0);
        if (U <= NT - 3)      asm volatile("s_waitcnt vmcnt(4)" ::: "memory");
        else if (U == NT - 2) asm volatile("s_waitcnt vmcnt(0)" ::: "memory");
        __builtin_amdgcn_s_barrier();
        __builtin_amdgcn_sched_barrier(0);
    }

#pragma unroll
    for (int r = 0; r < 4; ++r) {
        int v = 512 + m0v + waveA * 64 + r * 16 + quad * 4;
#pragma unroll
        for (int c = 0; c < 4; ++c) {
            int t = n0t + waveB * 64 + c * 16 + l16;
            float4 f;
            f.x = acc[r][c][0]; f.y = acc[r][c][1];
            f.z = acc[r][c][2]; f.w = acc[r][c][3];
            *(float4*)(out + ((size_t)b * SEQ + t) * 1024 + v) = f;
        }
    }
}

extern "C" void kernel_launch(void* const* d_in, const int* in_sizes, int n_in,
                              void* d_out, int out_size, void* d_ws, size_t ws_size,
                              hipStream_t stream) {
    const float* x  = (const float*)d_in[0];
    const float* Wq = (const float*)d_in[1];
    const float* bq = (const float*)d_in[2];
    const float* Wk = (const float*)d_in[3];
    const float* bk = (const float*)d_in[4];
    const float* Wv = (const float*)d_in[5];
    const float* bv = (const float*)d_in[6];
    float* out = (float*)d_out;

    char* ws = (char*)d_ws;
    const size_t QKV_BYTES = (size_t)ROWS * CH * 2;              // 16,777,216
    const size_t E_BYTES   = (size_t)BATCH * SEQ * SEQ * 2;      // 67,108,864
    unsigned short* qkv = (unsigned short*)ws;                   // q,k,v contiguous
    unsigned short* qb = qkv;
    unsigned short* kb = (unsigned short*)(ws + QKV_BYTES);
    unsigned short* vb = (unsigned short*)(ws + 2 * QKV_BYTES);
    unsigned short* E  = (unsigned short*)(ws + 3 * QKV_BYTES);
    float* Z = (float*)(ws + 3 * QKV_BYTES + E_BYTES);
    // Aliases (lifetimes disjoint on the in-order stream):
    unsigned short* xb = E;                                       // dead before logits writes E
    unsigned short* Wt = (unsigned short*)((char*)E + QKV_BYTES); // dead before logits writes E
    unsigned short* Vt = qb;                                      // qb dead after logits

    dim3 blk(256);
    fuse_x_kernel<<<dim3(4096), blk, 0, stream>>>(x, xb, out, Z);
    transpose_w_kernel<<<dim3(8, 8, 3), blk, 0, stream>>>(Wq, Wk, Wv, Wt);
    qkv8_kernel<<<dim3(384), dim3(512), 0, stream>>>(xb, Wt, bq, bk, bv, qkv);
    logits8_kernel<<<dim3(288), dim3(512), 0, stream>>>(qb, kb, E, Z);
    transpose_v_kernel<<<dim3(32, 8, 8), blk, 0, stream>>>(vb, Z, Vt);
    read8_kernel<<<dim3(512), blk, 0, stream>>>(E, Vt, out);
}

// Round 9
// 214.544 us; speedup vs baseline: 1.1151x; 1.1151x over previous
//
#include <hip/hip_runtime.h>
#include <hip/hip_bf16.h>
#include <math.h>

// Problem constants
#define BATCH 8
#define SEQ   2048
#define CH    512
#define ROWS  (BATCH * SEQ)   // 16384
#define INVSQ 0.044194173824159216f  // 1/sqrt(512)

#define TP 68                  // transpose-tile pitch (2-way conflict = free)
#define CPITCH 136             // C-bounce pitch in shorts (272 B, 16-B aligned)

typedef __attribute__((ext_vector_type(8))) __bf16 bf16x8;
typedef __attribute__((ext_vector_type(4))) float f32x4;

__device__ inline unsigned short f2bf(float f) {
    unsigned u = __builtin_bit_cast(unsigned, f);
    u += 0x7fffu + ((u >> 16) & 1u);   // round-to-nearest-even
    return (unsigned short)(u >> 16);
}
__device__ inline float bf2f(unsigned short s) {
    unsigned u = ((unsigned)s) << 16;
    return __builtin_bit_cast(float, u);
}

// ---------------------------------------------------------------------------
// fuse_x: x fp32 [16384,512] -> out[:, :, 0:512] (fp32) AND xb (bf16).
// Also zeroes Z (blocks 0..63).
// ---------------------------------------------------------------------------
__global__ __launch_bounds__(256) void fuse_x_kernel(
    const float* __restrict__ x, unsigned short* __restrict__ xb,
    float* __restrict__ out, float* __restrict__ Z)
{
    if (blockIdx.x < 64) Z[blockIdx.x * 256 + threadIdx.x] = 0.f;
    size_t base = ((size_t)blockIdx.x * 256 + threadIdx.x) * 8;
    size_t row = base >> 9, c = base & 511;
    float4 v0 = *(const float4*)(x + base);
    float4 v1 = *(const float4*)(x + base + 4);
    float* o = out + row * 1024 + c;
    *(float4*)o = v0;
    *(float4*)(o + 4) = v1;
    alignas(16) unsigned short t[8];
    t[0] = f2bf(v0.x); t[1] = f2bf(v0.y); t[2] = f2bf(v0.z); t[3] = f2bf(v0.w);
    t[4] = f2bf(v1.x); t[5] = f2bf(v1.y); t[6] = f2bf(v1.z); t[7] = f2bf(v1.w);
    *(uint4*)(xb + base) = *(const uint4*)t;
}

// ---------------------------------------------------------------------------
// transpose_w: W fp32 [512 k][512 n] -> Wt bf16 [3][512 n][512 k]
// ---------------------------------------------------------------------------
__global__ __launch_bounds__(256) void transpose_w_kernel(
    const float* __restrict__ Wq, const float* __restrict__ Wk,
    const float* __restrict__ Wv, unsigned short* __restrict__ Wt)
{
    __shared__ unsigned short T[64 * TP];
    const int k0 = blockIdx.x * 64, n0 = blockIdx.y * 64, w = blockIdx.z;
    const float* W = (w == 0) ? Wq : (w == 1) ? Wk : Wv;
    const int tid = threadIdx.x;
#pragma unroll
    for (int i = 0; i < 2; ++i) {
        int slot = tid + i * 256;
        int kr = slot >> 3, c8 = (slot & 7) << 3;
        float4 a = *(const float4*)(W + (size_t)(k0 + kr) * CH + n0 + c8);
        float4 b = *(const float4*)(W + (size_t)(k0 + kr) * CH + n0 + c8 + 4);
        T[(c8 + 0) * TP + kr] = f2bf(a.x); T[(c8 + 1) * TP + kr] = f2bf(a.y);
        T[(c8 + 2) * TP + kr] = f2bf(a.z); T[(c8 + 3) * TP + kr] = f2bf(a.w);
        T[(c8 + 4) * TP + kr] = f2bf(b.x); T[(c8 + 5) * TP + kr] = f2bf(b.y);
        T[(c8 + 6) * TP + kr] = f2bf(b.z); T[(c8 + 7) * TP + kr] = f2bf(b.w);
    }
    __syncthreads();
#pragma unroll
    for (int i = 0; i < 2; ++i) {
        int slot = tid + i * 256;
        int nr = slot >> 3, k8 = (slot & 7) << 3;
        uint2 lo = *(const uint2*)(T + nr * TP + k8);
        uint2 hi = *(const uint2*)(T + nr * TP + k8 + 4);
        uint4 u; u.x = lo.x; u.y = lo.y; u.z = hi.x; u.w = hi.y;
        *(uint4*)(Wt + ((size_t)w * CH + n0 + nr) * CH + k0 + k8) = u;
    }
}

// ---------------------------------------------------------------------------
// transpose_v: vb bf16 [b][s][v] -> Vt bf16 [b][v][s], scaled by 1/Z[b][s].
// ---------------------------------------------------------------------------
__global__ __launch_bounds__(256) void transpose_v_kernel(
    const unsigned short* __restrict__ vb, const float* __restrict__ Z,
    unsigned short* __restrict__ Vt)
{
    __shared__ unsigned short T[64 * TP];
    const int s0 = blockIdx.x * 64, v0 = blockIdx.y * 64, b = blockIdx.z;
    const int tid = threadIdx.x;
#pragma unroll
    for (int i = 0; i < 2; ++i) {
        int slot = tid + i * 256;
        int sr = slot >> 3, c8 = (slot & 7) << 3;
        float inv = 1.0f / Z[b * SEQ + s0 + sr];
        uint4 raw = *(const uint4*)(vb + ((size_t)b * SEQ + s0 + sr) * CH + v0 + c8);
        const unsigned short* p = (const unsigned short*)&raw;
#pragma unroll
        for (int j = 0; j < 8; ++j)
            T[(c8 + j) * TP + sr] = f2bf(bf2f(p[j]) * inv);
    }
    __syncthreads();
#pragma unroll
    for (int i = 0; i < 2; ++i) {
        int slot = tid + i * 256;
        int vr = slot >> 3, s8 = (slot & 7) << 3;
        uint2 lo = *(const uint2*)(T + vr * TP + s8);
        uint2 hi = *(const uint2*)(T + vr * TP + s8 + 4);
        uint4 u; u.x = lo.x; u.y = lo.y; u.z = hi.x; u.w = hi.y;
        *(uint4*)(Vt + ((size_t)b * CH + v0 + vr) * SEQ + s0 + s8) = u;
    }
}

// ---------------------------------------------------------------------------
// 128x128-tile BK=64 2-barrier counted-vmcnt pipeline, 256 thr / 4 waves.
// (Round-5 structure, best verified at 213.9 us.)
// LDS 64 KB: A[2][128][64] | B[2][128][64] bf16, 128-B rows.
// Swizzle (both sides, involution chunk^=(row&7) on 16-B slots).
// Per tile U: stageA(U+1); read 16 frags; lgkm(0); bar1; stageB(U+2);
// 32 MFMA; vmcnt(4) (tail vmcnt(0) at NT-2); bar2.
// ---------------------------------------------------------------------------
#define FRAG_READS                                                            \
    bf16x8 a0[4], a1[4], c0[4], c1[4];                                        \
    _Pragma("unroll")                                                         \
    for (int rr = 0; rr < 4; ++rr) {                                          \
        const unsigned short* ap = Ab + (arow + rr * 16) * 64;                \
        const unsigned short* bp = Bb + (brow + rr * 16) * 64;                \
        a0[rr] = *(const bf16x8*)(ap + s80);                                  \
        a1[rr] = *(const bf16x8*)(ap + s81);                                  \
        c0[rr] = *(const bf16x8*)(bp + s80);                                  \
        c1[rr] = *(const bf16x8*)(bp + s81);                                  \
    }

#define MFMA_TILE                                                             \
    _Pragma("unroll")                                                         \
    for (int rr = 0; rr < 4; ++rr)                                            \
        _Pragma("unroll")                                                     \
        for (int cc = 0; cc < 4; ++cc)                                        \
            acc[rr][cc] = __builtin_amdgcn_mfma_f32_16x16x32_bf16(            \
                a0[rr], c0[cc], acc[rr][cc], 0, 0, 0);                        \
    _Pragma("unroll")                                                         \
    for (int rr = 0; rr < 4; ++rr)                                            \
        _Pragma("unroll")                                                     \
        for (int cc = 0; cc < 4; ++cc)                                        \
            acc[rr][cc] = __builtin_amdgcn_mfma_f32_16x16x32_bf16(            \
                a1[rr], c1[cc], acc[rr][cc], 0, 0, 0);

#define STAGE4(gsrc, dslab)                                                   \
    _Pragma("unroll")                                                         \
    for (int p = 0; p < 4; ++p)                                               \
        __builtin_amdgcn_global_load_lds(                                     \
            (const __attribute__((address_space(1))) unsigned int*)((gsrc) + (size_t)p * 32 * gstride), \
            (__attribute__((address_space(3))) unsigned int*)((dslab) + p * 2048 + (tid << 3)), \
            16, 0, 0);

#define PIPE_PROLOGUE                                                         \
    stageA(0); stageB(0); stageB(1);                                          \
    asm volatile("s_waitcnt vmcnt(4)" ::: "memory");                          \
    __builtin_amdgcn_s_barrier();                                             \
    __builtin_amdgcn_sched_barrier(0);

#define PIPE_BODY(NTv)                                                        \
    {                                                                         \
        const unsigned short* Ab = lds + (U & 1) * 8192;                      \
        const unsigned short* Bb = lds + 16384 + (U & 1) * 8192;              \
        stageA(U + 1);                                                        \
        FRAG_READS                                                            \
        asm volatile("s_waitcnt lgkmcnt(0)" ::: "memory");                    \
        __builtin_amdgcn_s_barrier();                                         \
        __builtin_amdgcn_sched_barrier(0);                                    \
        stageB(U + 2);                                                        \
        __builtin_amdgcn_s_setprio(1);                                        \
        MFMA_TILE                                                             \
        __builtin_amdgcn_s_setprio(0);                                        \
        if (U <= (NTv) - 3)      asm volatile("s_waitcnt vmcnt(4)" ::: "memory"); \
        else if (U == (NTv) - 2) asm volatile("s_waitcnt vmcnt(0)" ::: "memory"); \
        __builtin_amdgcn_s_barrier();                                         \
        __builtin_amdgcn_sched_barrier(0);                                    \
    }

// ---------------------------------------------------------------------------
// qkv fused GEMM. C[wr(weight row), m(x row)]: A = Wt [1536][512] k-major,
// B = xb [16384][512]. Tile 128(w) x 128(x), BK=64, 8 K-tiles.
// Grid 1536 = 128 xt x 12 wt; bijective XCD swizzle (1536 = 8 x 192).
// Epilogue: LDS-bounce coalesced store (full 128-B lines per row) to kill
// the measured 1.96x write amplification of scattered uint2 stores.
// ---------------------------------------------------------------------------
__global__ __launch_bounds__(256, 2) void qkv8_kernel(
    const unsigned short* __restrict__ xb, const unsigned short* __restrict__ Wt,
    const float* __restrict__ bq, const float* __restrict__ bk,
    const float* __restrict__ bv, unsigned short* __restrict__ qkv)
{
    __shared__ unsigned short lds[32768];   // 64 KB
    const int tid = threadIdx.x;
    const int lane = tid & 63, wave = tid >> 6;
    const int waveA = wave >> 1;            // 0..1: weight strip (64 rows)
    const int waveB = wave & 1;             // 0..1: x strip (64 rows)
    const int quad = lane >> 4, l16 = lane & 15;

    int id = (int)blockIdx.x;
    id = (id & 7) * 192 + (id >> 3);        // XCD c owns x-tiles 16c..16c+15
    const int xt = id / 12, wt = id - xt * 12;
    const int xrow0 = xt << 7, wrow0 = wt << 7;

    const size_t gstride = CH;
    const unsigned short* __restrict__ Wg = Wt + (size_t)wrow0 * CH;
    const unsigned short* __restrict__ Xg = xb + (size_t)xrow0 * CH;

    // Staging: rows tid>>3 (+32 per pass), source chunk pre-swizzled.
    const int scol = (((tid & 7) ^ ((tid >> 3) & 7)) << 3);
    const size_t ga = (size_t)(tid >> 3) * gstride + scol;
    // Read-side swizzle: slot (h*4+quad)^(row&7), row&7 == l16&7.
    const int s80 = ((quad ^ (l16 & 7)) << 3);
    const int s81 = s80 ^ 32;
    const int arow = waveA * 64 + l16;
    const int brow = waveB * 64 + l16;

    f32x4 acc[4][4] = {};

    auto stageA = [&](int V) {
        if (V >= 8) return;
        const unsigned short* g = Wg + ga + V * 64;
        unsigned short* d = lds + (V & 1) * 8192;
        STAGE4(g, d)
    };
    auto stageB = [&](int V) {
        if (V >= 8) return;
        const unsigned short* g = Xg + ga + V * 64;
        unsigned short* d = lds + 16384 + (V & 1) * 8192;
        STAGE4(g, d)
    };

    PIPE_PROLOGUE
#pragma unroll
    for (int U = 0; U < 8; ++U) PIPE_BODY(8)

    const int which = wrow0 >> 9;   // uniform per block
    const float* bias = (which == 0) ? bq : (which == 1) ? bk : bv;
    const float scale = (which == 0) ? INVSQ : 1.0f;
    const int colblk = wrow0 & 511;

    // ---- coalesced epilogue via LDS bounce (LDS is dead after K-loop:
    // all ds_reads drained at bar1 of last tile, DMA count 0 at final bar) ----
#pragma unroll
    for (int r = 0; r < 4; ++r) {
        int cl = waveA * 64 + r * 16 + quad * 4;          // local col 0..127
        float4 b4 = *(const float4*)(bias + colblk + cl);
#pragma unroll
        for (int c = 0; c < 4; ++c) {
            int ml = waveB * 64 + c * 16 + l16;           // local row 0..127
            alignas(8) unsigned short pk[4];
            pk[0] = f2bf((acc[r][c][0] + b4.x) * scale);
            pk[1] = f2bf((acc[r][c][1] + b4.y) * scale);
            pk[2] = f2bf((acc[r][c][2] + b4.z) * scale);
            pk[3] = f2bf((acc[r][c][3] + b4.w) * scale);
            *(uint2*)(lds + ml * CPITCH + cl) = *(const uint2*)pk;
        }
    }
    __syncthreads();
    {
        unsigned short* outw = qkv + (size_t)which * ROWS * CH;
        const int row = tid >> 1, half = tid & 1;
        const unsigned short* src = lds + row * CPITCH + half * 64;
        unsigned short* dst = outw + (size_t)(xrow0 + row) * CH + colblk + half * 64;
#pragma unroll
        for (int j = 0; j < 8; ++j)
            *(uint4*)(dst + j * 8) = *(const uint4*)(src + j * 8);
    }
}

// ---------------------------------------------------------------------------
// logits, pipelined: C[s][t] = k_s . q_t (q pre-scaled by INVSQ).
// A = K-tile [128 s][512 k], B = Q-tile [128 t][512 k]. Triangle st<=tt:
// 136 pairs x 8 b = 1088 blocks. b = blockIdx&7 pins batch to XCD.
// E[t][s] = exp(C) if s<=t else 0; Z[s] via shuffle+atomic.
// Epilogue: Z arithmetic unchanged; E written via LDS bounce, one
// contiguous 256-B run per t-row (vs scattered uint2).
// ---------------------------------------------------------------------------
__global__ __launch_bounds__(256, 2) void logits8_kernel(
    const unsigned short* __restrict__ qb, const unsigned short* __restrict__ kb,
    unsigned short* __restrict__ E, float* __restrict__ Z)
{
    __shared__ unsigned short lds[32768];   // 64 KB
    const int tid = threadIdx.x;
    const int lane = tid & 63, wave = tid >> 6;
    const int waveA = wave >> 1;            // 0..1: s strip
    const int waveB = wave & 1;             // 0..1: t strip
    const int quad = lane >> 4, l16 = lane & 15;

    const int b = (int)blockIdx.x & 7;
    const int i = (int)blockIdx.x >> 3;     // 0..135 triangle index
    int tt = (int)((sqrtf(8.f * (float)i + 1.f) - 1.f) * 0.5f);
    int st = i - ((tt * (tt + 1)) >> 1);
    while (st < 0)  { --tt; st = i - ((tt * (tt + 1)) >> 1); }
    while (st > tt) { ++tt; st = i - ((tt * (tt + 1)) >> 1); }
    const int m0s = st << 7;    // s rows (A, from k)
    const int n0t = tt << 7;    // t rows (B, from q)

    const size_t gstride = CH;
    const unsigned short* __restrict__ Ag = kb + ((size_t)b * SEQ + m0s) * CH;
    const unsigned short* __restrict__ Bg = qb + ((size_t)b * SEQ + n0t) * CH;

    const int scol = (((tid & 7) ^ ((tid >> 3) & 7)) << 3);
    const size_t ga = (size_t)(tid >> 3) * gstride + scol;
    const int s80 = ((quad ^ (l16 & 7)) << 3);
    const int s81 = s80 ^ 32;
    const int arow = waveA * 64 + l16;
    const int brow = waveB * 64 + l16;

    f32x4 acc[4][4] = {};

    auto stageA = [&](int V) {
        if (V >= 8) return;
        const unsigned short* g = Ag + ga + V * 64;
        unsigned short* d = lds + (V & 1) * 8192;
        STAGE4(g, d)
    };
    auto stageB = [&](int V) {
        if (V >= 8) return;
        const unsigned short* g = Bg + ga + V * 64;
        unsigned short* d = lds + 16384 + (V & 1) * 8192;
        STAGE4(g, d)
    };

    PIPE_PROLOGUE
#pragma unroll
    for (int U = 0; U < 8; ++U) PIPE_BODY(8)

    // Epilogue: causal mask, exp, Z partial sums (unchanged), then E via
    // LDS bounce + coalesced row stores.
#pragma unroll
    for (int r = 0; r < 4; ++r) {
        int sb = m0s + waveA * 64 + r * 16 + quad * 4;
        int sl = waveA * 64 + r * 16 + quad * 4;          // local s col 0..127
        float ev[4][4];
#pragma unroll
        for (int c = 0; c < 4; ++c) {
            int t = n0t + waveB * 64 + c * 16 + l16;
#pragma unroll
            for (int reg = 0; reg < 4; ++reg)
                ev[c][reg] = (sb + reg <= t) ? __expf(acc[r][c][reg]) : 0.f;
        }
#pragma unroll
        for (int reg = 0; reg < 4; ++reg) {
            float z = ev[0][reg] + ev[1][reg] + ev[2][reg] + ev[3][reg];
            z += __shfl_xor(z, 1);
            z += __shfl_xor(z, 2);
            z += __shfl_xor(z, 4);
            z += __shfl_xor(z, 8);
            if (l16 == 0) atomicAdd(&Z[b * SEQ + sb + reg], z);
        }
#pragma unroll
        for (int c = 0; c < 4; ++c) {
            int tl = waveB * 64 + c * 16 + l16;           // local t row 0..127
            alignas(8) unsigned short pk[4];
            pk[0] = f2bf(ev[c][0]); pk[1] = f2bf(ev[c][1]);
            pk[2] = f2bf(ev[c][2]); pk[3] = f2bf(ev[c][3]);
            *(uint2*)(lds + tl * CPITCH + sl) = *(const uint2*)pk;
        }
    }
    __syncthreads();
    {
        const int row = tid >> 1, half = tid & 1;
        const unsigned short* src = lds + row * CPITCH + half * 64;
        unsigned short* dst = E + ((size_t)b * SEQ + n0t + row) * SEQ + m0s + half * 64;
#pragma unroll
        for (int j = 0; j < 8; ++j)
            *(uint4*)(dst + j * 8) = *(const uint4*)(src + j * 8);
    }
}

// ---------------------------------------------------------------------------
// read, pipelined (round-5 version, verified): C[v][t] = sum_s Vt[v][s] *
// E[t][s]. A = Vt tile [128 v][s], B = E tile [128 t][s], both stride SEQ.
// BK=64, runtime NT = 2*(tt+1). Grid 512, b = blockIdx&7 pins XCD.
// float4 stores already coalesced (WRITE_SIZE ~= ideal, measured).
// ---------------------------------------------------------------------------
__global__ __launch_bounds__(256, 2) void read8_kernel(
    const unsigned short* __restrict__ E, const unsigned short* __restrict__ Vt,
    float* __restrict__ out)
{
    __shared__ unsigned short lds[32768];   // 64 KB
    const int tid = threadIdx.x;
    const int lane = tid & 63, wave = tid >> 6;
    const int waveA = wave >> 1;            // 0..1: v strip
    const int waveB = wave & 1;             // 0..1: t strip
    const int quad = lane >> 4, l16 = lane & 15;

    const int id = blockIdx.x;
    const int b = id & 7;
    const int rem = id >> 3;
    const int mv = rem & 3;                  // v tile (4)
    const int r0 = rem >> 2;                 // 0..15
    const int tt = (r0 < 8) ? r0 : 23 - r0;  // paired so per-CU work balances
    const int m0v = mv << 7;
    const int n0t = tt << 7;
    const int NT = (tt + 1) * 2;             // K-tiles of 64 (causal extent)

    const size_t gstride = SEQ;
    const unsigned short* __restrict__ Ag = Vt + ((size_t)b * CH + m0v) * SEQ;
    const unsigned short* __restrict__ Bg = E + ((size_t)b * SEQ + n0t) * SEQ;

    const int scol = (((tid & 7) ^ ((tid >> 3) & 7)) << 3);
    const size_t ga = (size_t)(tid >> 3) * gstride + scol;
    const int s80 = ((quad ^ (l16 & 7)) << 3);
    const int s81 = s80 ^ 32;
    const int arow = waveA * 64 + l16;
    const int brow = waveB * 64 + l16;

    f32x4 acc[4][4] = {};

    auto stageA = [&](int V) {
        if (V >= NT) return;
        const unsigned short* g = Ag + ga + V * 64;
        unsigned short* d = lds + (V & 1) * 8192;
        STAGE4(g, d)
    };
    auto stageB = [&](int V) {
        if (V >= NT) return;
        const unsigned short* g = Bg + ga + V * 64;
        unsigned short* d = lds + 16384 + (V & 1) * 8192;
        STAGE4(g, d)
    };

    PIPE_PROLOGUE
#pragma unroll 2
    for (int U = 0; U < NT; ++U) PIPE_BODY(NT)

#pragma unroll
    for (int r = 0; r < 4; ++r) {
        int v = 512 + m0v + waveA * 64 + r * 16 + quad * 4;
#pragma unroll
        for (int c = 0; c < 4; ++c) {
            int t = n0t + waveB * 64 + c * 16 + l16;
            float4 f;
            f.x = acc[r][c][0]; f.y = acc[r][c][1];
            f.z = acc[r][c][2]; f.w = acc[r][c][3];
            *(float4*)(out + ((size_t)b * SEQ + t) * 1024 + v) = f;
        }
    }
}

extern "C" void kernel_launch(void* const* d_in, const int* in_sizes, int n_in,
                              void* d_out, int out_size, void* d_ws, size_t ws_size,
                              hipStream_t stream) {
    const float* x  = (const float*)d_in[0];
    const float* Wq = (const float*)d_in[1];
    const float* bq = (const float*)d_in[2];
    const float* Wk = (const float*)d_in[3];
    const float* bk = (const float*)d_in[4];
    const float* Wv = (const float*)d_in[5];
    const float* bv = (const float*)d_in[6];
    float* out = (float*)d_out;

    char* ws = (char*)d_ws;
    const size_t QKV_BYTES = (size_t)ROWS * CH * 2;              // 16,777,216
    const size_t E_BYTES   = (size_t)BATCH * SEQ * SEQ * 2;      // 67,108,864
    unsigned short* qkv = (unsigned short*)ws;                   // q,k,v contiguous
    unsigned short* qb = qkv;
    unsigned short* kb = (unsigned short*)(ws + QKV_BYTES);
    unsigned short* vb = (unsigned short*)(ws + 2 * QKV_BYTES);
    unsigned short* E  = (unsigned short*)(ws + 3 * QKV_BYTES);
    float* Z = (float*)(ws + 3 * QKV_BYTES + E_BYTES);
    // Aliases (lifetimes disjoint on the in-order stream):
    unsigned short* xb = E;                                       // dead before logits writes E
    unsigned short* Wt = (unsigned short*)((char*)E + QKV_BYTES); // dead before logits writes E
    unsigned short* Vt = qb;                                      // qb dead after logits

    dim3 blk(256);
    fuse_x_kernel<<<dim3(4096), blk, 0, stream>>>(x, xb, out, Z);
    transpose_w_kernel<<<dim3(8, 8, 3), blk, 0, stream>>>(Wq, Wk, Wv, Wt);
    qkv8_kernel<<<dim3(1536), blk, 0, stream>>>(xb, Wt, bq, bk, bv, qkv);
    logits8_kernel<<<dim3(1088), blk, 0, stream>>>(qb, kb, E, Z);
    transpose_v_kernel<<<dim3(32, 8, 8), blk, 0, stream>>>(vb, Z, Vt);
    read8_kernel<<<dim3(512), blk, 0, stream>>>(E, Vt, out);
}